// Round 8
// baseline (113.261 us; speedup 1.0000x reference)
//
#include <hip/hip_runtime.h>
#include <hip/hip_bf16.h>

#define L_DIM 2048
#define D_DIM 2048
#define B_DIM 2
#define H_DIM 8
#define NT 16            // 2048/128 tiles per dim
#define NPAIR 136        // NT*(NT+1)/2 triangular tiles
#define NRED 512         // total reducer slots per batch (8 exact iters each)
#define NRED_A 128       // reducer slots done in k_prep (25% of attn)
#define NRED_B (NRED - NRED_A)
#define NKT (D_DIM / 32) // 64 K-steps
#define EPSV 1e-6f

using bf16x8 = __attribute__((ext_vector_type(8))) __bf16;
using f32x4  = __attribute__((ext_vector_type(4))) float;
using f4     = __attribute__((ext_vector_type(4))) float;

__device__ inline void gload_lds16(const void* g, void* l) {
    __builtin_amdgcn_global_load_lds(
        (const __attribute__((address_space(1))) void*)g,
        (__attribute__((address_space(3))) void*)l, 16, 0, 0);
}

// round-to-nearest-even f32 -> bf16 (finite inputs)
__device__ inline ushort f2bf(float f) {
    unsigned int u = __float_as_uint(f);
    unsigned int lsb = (u >> 16) & 1u;
    u += 0x7fffu + lsb;
    return (ushort)(u >> 16);
}
__device__ inline float bf2f(ushort u) {
    return __uint_as_float(((unsigned int)u) << 16);
}

// reducer body: Amean[b,l,c] = mean_h attn[b,h,l,c] for interleaved chunk rid
__device__ inline void reduce_chunk(const float* __restrict__ attn, ushort* __restrict__ Amean,
                                    int batch, int rid, int t) {
    const float* ab = attn + (size_t)batch * H_DIM * L_DIM * L_DIM;
    ushort* am = Amean + (size_t)batch * L_DIM * L_DIM;
    int i = rid * 256 + t;
    #pragma unroll
    for (int j = 0; j < 8; ++j, i += NRED * 256) {   // 8 exact iters cover chunk
        float4 s = {0.f, 0.f, 0.f, 0.f};
        #pragma unroll
        for (int h = 0; h < H_DIM; ++h) {
            // attn is single-use streaming: bypass LLC so xu/K/Amean stay resident
            const f4 v = __builtin_nontemporal_load(
                ((const f4*)(ab + (size_t)h * L_DIM * L_DIM)) + i);
            s.x += v.x; s.y += v.y; s.z += v.z; s.w += v.w;
        }
        ushort4 o;
        o.x = f2bf(s.x * 0.125f); o.y = f2bf(s.y * 0.125f);
        o.z = f2bf(s.z * 0.125f); o.w = f2bf(s.w * 0.125f);
        ((ushort4*)am)[i] = o;               // cached: re-read by epilogue
    }
}

// ---- K_prep mixed grid: [0, 2*NRED_A) attn reducers | [.., +4096) row-normalize -----
__global__ __launch_bounds__(256) void k_prep(const float* __restrict__ x,
                                              const float* __restrict__ attn,
                                              ushort* __restrict__ xu,
                                              double* __restrict__ sums,
                                              ushort* __restrict__ Amean) {
    const int t = threadIdx.x;
    const int bid = blockIdx.x;
    if (bid < 2 * NRED_A) {
        reduce_chunk(attn, Amean, bid >> 7, bid & (NRED_A - 1), t);
        return;
    }
    const int row = bid - 2 * NRED_A;      // b*L + l
    const float* xr = x + (size_t)row * D_DIM;
    f4 v0 = __builtin_nontemporal_load(((const f4*)xr) + t);        // x single-use
    f4 v1 = __builtin_nontemporal_load(((const f4*)xr) + t + 256);
    float ss = v0.x*v0.x + v0.y*v0.y + v0.z*v0.z + v0.w*v0.w
             + v1.x*v1.x + v1.y*v1.y + v1.z*v1.z + v1.w*v1.w;
    #pragma unroll
    for (int off = 32; off; off >>= 1) ss += __shfl_down(ss, off);
    __shared__ float red[4];
    __shared__ float s_inv;
    if ((t & 63) == 0) red[t >> 6] = ss;
    __syncthreads();
    if (t == 0) {
        float nrm = sqrtf(red[0] + red[1] + red[2] + red[3]);
        nrm = fmaxf(nrm, EPSV);
        s_inv = 1.0f / nrm;
        if (row == 0) { sums[0] = 0.0; sums[1] = 0.0; sums[2] = 0.0; sums[3] = 0.0; }
    }
    __syncthreads();
    const float inv = s_inv;
    ushort* xo = xu + (size_t)row * D_DIM;
    ushort4 o0, o1;
    o0.x = f2bf(v0.x * inv); o0.y = f2bf(v0.y * inv);
    o0.z = f2bf(v0.z * inv); o0.w = f2bf(v0.w * inv);
    o1.x = f2bf(v1.x * inv); o1.y = f2bf(v1.y * inv);
    o1.z = f2bf(v1.z * inv); o1.w = f2bf(v1.w * inv);
    ((ushort4*)xo)[t]       = o0;    // cached: GEMM's hot working set
    ((ushort4*)xo)[t + 256] = o1;
}

// ---- K2 mixed grid: [0,NPAIR) sym GEMM tiles | [NPAIR,+NRED_B) attn reducers --------
__global__ __launch_bounds__(256) void k_mixed(const ushort* __restrict__ Xu,
                                               const float* __restrict__ attn,
                                               ushort* __restrict__ K16,
                                               double* __restrict__ sums,
                                               ushort* __restrict__ Amean) {
    __shared__ __align__(16) ushort lds_a[2][128 * 32];
    __shared__ __align__(16) ushort lds_b[2][128 * 32];
    const int t = threadIdx.x;
    const int batch = blockIdx.z;

    if (blockIdx.x >= NPAIR) {
        reduce_chunk(attn, Amean, batch, NRED_A + (blockIdx.x - NPAIR), t);
        return;
    }

    // ---------------- GEMM tile (upper-triangular + mirror), 2-phase pipelined -------
    const int lane = t & 63;
    const int w    = t >> 6;
    const int wr   = w >> 1, wc = w & 1;       // 2x2 waves, 64x64 each
    int ti = 0, rem = blockIdx.x;
    while (rem >= NT - ti) { rem -= NT - ti; ++ti; }
    const int tj = ti + rem;
    const int bRow = ti * 128;
    const int bCol = tj * 128;
    const bool diag = (ti == tj);
    const ushort* Xb = Xu + (size_t)batch * L_DIM * D_DIM;

    const int srow = t >> 2;                   // 0..63 panel row
    // store-side swizzle: LDS slot (t&3) of row srow receives chunk (t&3)^((srow>>1)&3)
    const int scol = ((t & 3) ^ ((srow >> 1) & 3)) * 8;
    const ushort* gA0 = Xb + (size_t)(bRow + srow)      * D_DIM + scol;
    const ushort* gA1 = Xb + (size_t)(bRow + 64 + srow) * D_DIM + scol;
    const ushort* gB0 = Xb + (size_t)(bCol + srow)      * D_DIM + scol;
    const ushort* gB1 = Xb + (size_t)(bCol + 64 + srow) * D_DIM + scol;
    const int ldst = t * 8;

    f32x4 acc[4][4] = {};
    const int frow = lane & 15;
    const int fk   = lane >> 4;
    const int fx   = (frow >> 1) & 3;          // read-side XOR key (conflict-free)

    auto STAGE = [&](int buf, int kt) {
        const size_t ko = (size_t)kt * 32;
        gload_lds16(gA0 + ko, &lds_a[buf][ldst]);
        gload_lds16(gA1 + ko, &lds_a[buf][64 * 32 + ldst]);
        gload_lds16(gB0 + ko, &lds_b[buf][ldst]);
        gload_lds16(gB1 + ko, &lds_b[buf][64 * 32 + ldst]);
    };
    auto COMPUTE = [&](int buf) {
        bf16x8 a[4], b[4];
        #pragma unroll
        for (int m = 0; m < 4; ++m)
            a[m] = *(const bf16x8*)&lds_a[buf][(wr * 64 + m * 16 + frow) * 32 + (fk ^ fx) * 8];
        #pragma unroll
        for (int n = 0; n < 4; ++n)
            b[n] = *(const bf16x8*)&lds_b[buf][(wc * 64 + n * 16 + frow) * 32 + (fk ^ fx) * 8];
        #pragma unroll
        for (int m = 0; m < 4; ++m)
            #pragma unroll
            for (int n = 0; n < 4; ++n)
                acc[m][n] = __builtin_amdgcn_mfma_f32_16x16x32_bf16(a[m], b[n], acc[m][n], 0, 0, 0);
    };

    STAGE(0, 0);
    __syncthreads();
    for (int kt = 0; kt < NKT; kt += 2) {
        STAGE(1, kt + 1);
        COMPUTE(0);
        __syncthreads();
        if (kt + 2 < NKT) STAGE(0, kt + 2);
        COMPUTE(1);
        __syncthreads();
    }

    ushort* Kb = K16 + (size_t)batch * L_DIM * L_DIM;
    float ps = 0.f, pss = 0.f;
    #pragma unroll
    for (int m = 0; m < 4; ++m) {
        #pragma unroll
        for (int n = 0; n < 4; ++n) {
            #pragma unroll
            for (int j = 0; j < 4; ++j) {
                const int r = bRow + wr * 64 + m * 16 + fk * 4 + j;
                const int c = bCol + wc * 64 + n * 16 + frow;
                const float v = acc[m][n][j];
                Kb[(size_t)r * L_DIM + c] = f2bf(v);   // bf16 intermediate (LLC-hot)
                ps += v; pss += v * v;
            }
            if (!diag) {
                // mirror: K[c][r..r+3] = acc[m][n][0..3] — contiguous ushort4 (8 B)
                const int rr  = bCol + wc * 64 + n * 16 + frow;
                const int cc0 = bRow + wr * 64 + m * 16 + fk * 4;
                ushort4 mq;
                mq.x = f2bf(acc[m][n][0]); mq.y = f2bf(acc[m][n][1]);
                mq.z = f2bf(acc[m][n][2]); mq.w = f2bf(acc[m][n][3]);
                *(ushort4*)&Kb[(size_t)rr * L_DIM + cc0] = mq;
            }
        }
    }
    if (!diag) { ps *= 2.f; pss *= 2.f; }      // off-diag values appear twice in K
    #pragma unroll
    for (int off = 32; off; off >>= 1) {
        ps  += __shfl_down(ps, off);
        pss += __shfl_down(pss, off);
    }
    __shared__ float redS[4], redSS[4];
    if (lane == 0) { redS[w] = ps; redSS[w] = pss; }
    __syncthreads();
    if (t == 0) {
        atomicAdd(&sums[batch * 2],     (double)(redS[0] + redS[1] + redS[2] + redS[3]));
        atomicAdd(&sums[batch * 2 + 1], (double)(redSS[0] + redSS[1] + redSS[2] + redSS[3]));
    }
}

// ------- K3: K_norm (f32, nt) from bf16 K; dot(Amean,K) -> cos_align, gate -----------
__global__ __launch_bounds__(256) void k_epilogue(float* __restrict__ out,
                                                  const ushort* __restrict__ K16,
                                                  const ushort* __restrict__ Amean,
                                                  const double* __restrict__ sums,
                                                  const float* __restrict__ Wp,
                                                  const float* __restrict__ bp) {
    const int row = blockIdx.x;              // b*L + l
    const int b = row >> 11;
    const int t = threadIdx.x;

    const double N = (double)L_DIM * (double)L_DIM;
    const double mean_d = sums[b * 2] / N;
    double var = (sums[b * 2 + 1] - N * mean_d * mean_d) / (N - 1.0);
    var = var > 0.0 ? var : 0.0;
    float sd = (float)sqrt(var);
    sd = fmaxf(sd, EPSV);
    const float inv_std = 1.0f / sd;
    const float mean = (float)mean_d;

    const ushort* krow = K16 + (size_t)row * L_DIM;
    const ushort* arow = Amean + (size_t)row * L_DIM;
    float* onrm = out + 2 * B_DIM * L_DIM + (size_t)row * L_DIM;

    // 8 elements per thread (both LLC-hot reads), f32 nt store
    const ushort4 k0 = ((const ushort4*)krow)[t * 2];
    const ushort4 k1 = ((const ushort4*)krow)[t * 2 + 1];
    const ushort4 a0 = ((const ushort4*)arow)[t * 2];
    const ushort4 a1 = ((const ushort4*)arow)[t * 2 + 1];
    float kf[8] = { bf2f(k0.x), bf2f(k0.y), bf2f(k0.z), bf2f(k0.w),
                    bf2f(k1.x), bf2f(k1.y), bf2f(k1.z), bf2f(k1.w) };
    float af[8] = { bf2f(a0.x), bf2f(a0.y), bf2f(a0.z), bf2f(a0.w),
                    bf2f(a1.x), bf2f(a1.y), bf2f(a1.z), bf2f(a1.w) };
    float dot = 0.f;
    #pragma unroll
    for (int j = 0; j < 8; ++j) dot += af[j] * kf[j];
    f4 n0, n1;
    n0.x = (kf[0] - mean) * inv_std; n0.y = (kf[1] - mean) * inv_std;
    n0.z = (kf[2] - mean) * inv_std; n0.w = (kf[3] - mean) * inv_std;
    n1.x = (kf[4] - mean) * inv_std; n1.y = (kf[5] - mean) * inv_std;
    n1.z = (kf[6] - mean) * inv_std; n1.w = (kf[7] - mean) * inv_std;
    // K_norm written once, never re-read: non-temporal
    __builtin_nontemporal_store(n0, ((f4*)onrm) + t * 2);
    __builtin_nontemporal_store(n1, ((f4*)onrm) + t * 2 + 1);

    #pragma unroll
    for (int off = 32; off; off >>= 1) dot += __shfl_down(dot, off);
    __shared__ float red[4];
    if ((t & 63) == 0) red[t >> 6] = dot;
    __syncthreads();
    if (t == 0) {
        const float dotv = red[0] + red[1] + red[2] + red[3];
        const float ca = (dotv - mean) * inv_std;      // uses sum_c A == 1
        out[B_DIM * L_DIM + row] = ca;                 // cos_align
        const float z = Wp[0] * ca + bp[0];
        out[row] = 1.0f / (1.0f + expf(-z));           // gate
    }
}

extern "C" void kernel_launch(void* const* d_in, const int* in_sizes, int n_in,
                              void* d_out, int out_size, void* d_ws, size_t ws_size,
                              hipStream_t stream) {
    const float* x    = (const float*)d_in[0];
    const float* attn = (const float*)d_in[1];
    const float* W    = (const float*)d_in[2];
    const float* bb   = (const float*)d_in[3];
    float* out = (float*)d_out;

    const size_t MAT = (size_t)B_DIM * L_DIM * L_DIM;                 // 8.4M elems
    ushort* xu    = (ushort*)d_ws;                                    // 16.8 MB bf16
    double* sums  = (double*)((char*)d_ws + MAT * 2);
    ushort* Amean = (ushort*)((char*)d_ws + MAT * 2 + 256);           // 16.8 MB bf16
    ushort* K16   = (ushort*)((char*)d_ws + MAT * 4 + 256);           // 16.8 MB bf16

    hipLaunchKernelGGL(k_prep, dim3(2 * NRED_A + B_DIM * L_DIM), dim3(256), 0, stream,
                       x, attn, xu, sums, Amean);
    hipLaunchKernelGGL(k_mixed, dim3(NPAIR + NRED_B, 1, B_DIM), dim3(256), 0, stream,
                       xu, attn, K16, sums, Amean);
    hipLaunchKernelGGL(k_epilogue, dim3(B_DIM * L_DIM), dim3(256), 0, stream,
                       out, K16, Amean, sums, W, bb);
}

// Round 9
// 106.103 us; speedup vs baseline: 1.0675x; 1.0675x over previous
//
#include <hip/hip_runtime.h>
#include <hip/hip_bf16.h>

#define L_DIM 2048
#define D_DIM 2048
#define B_DIM 2
#define H_DIM 8
#define NT 16            // 2048/128 tiles per dim
#define NPAIR 136        // NT*(NT+1)/2 triangular tiles
#define NRED 512         // reducer blocks per batch (8 exact iters each)
#define NKT (D_DIM / 64) // 32 K-steps at BK=64
#define EPSV 1e-6f

using bf16x8 = __attribute__((ext_vector_type(8))) __bf16;
using f32x4  = __attribute__((ext_vector_type(4))) float;
using f4     = __attribute__((ext_vector_type(4))) float;

__device__ inline void gload_lds16(const void* g, void* l) {
    __builtin_amdgcn_global_load_lds(
        (const __attribute__((address_space(1))) void*)g,
        (__attribute__((address_space(3))) void*)l, 16, 0, 0);
}

// round-to-nearest-even f32 -> bf16 (finite inputs)
__device__ inline ushort f2bf(float f) {
    unsigned int u = __float_as_uint(f);
    unsigned int lsb = (u >> 16) & 1u;
    u += 0x7fffu + lsb;
    return (ushort)(u >> 16);
}
__device__ inline float bf2f(ushort u) {
    return __uint_as_float(((unsigned int)u) << 16);
}

// ---------------- K1: row-normalize x -> bf16; zero the f64 accumulators -------------
__global__ __launch_bounds__(256) void k_normalize(const float* __restrict__ x,
                                                   ushort* __restrict__ xu,
                                                   double* __restrict__ sums) {
    const int row = blockIdx.x;            // b*L + l
    const int t   = threadIdx.x;
    const float* xr = x + (size_t)row * D_DIM;
    f4 v0 = __builtin_nontemporal_load(((const f4*)xr) + t);        // x single-use
    f4 v1 = __builtin_nontemporal_load(((const f4*)xr) + t + 256);
    float ss = v0.x*v0.x + v0.y*v0.y + v0.z*v0.z + v0.w*v0.w
             + v1.x*v1.x + v1.y*v1.y + v1.z*v1.z + v1.w*v1.w;
    #pragma unroll
    for (int off = 32; off; off >>= 1) ss += __shfl_down(ss, off);
    __shared__ float red[4];
    __shared__ float s_inv;
    if ((t & 63) == 0) red[t >> 6] = ss;
    __syncthreads();
    if (t == 0) {
        float nrm = sqrtf(red[0] + red[1] + red[2] + red[3]);
        nrm = fmaxf(nrm, EPSV);
        s_inv = 1.0f / nrm;
        if (row == 0) { sums[0] = 0.0; sums[1] = 0.0; sums[2] = 0.0; sums[3] = 0.0; }
    }
    __syncthreads();
    const float inv = s_inv;
    ushort* xo = xu + (size_t)row * D_DIM;
    ushort4 o0, o1;
    o0.x = f2bf(v0.x * inv); o0.y = f2bf(v0.y * inv);
    o0.z = f2bf(v0.z * inv); o0.w = f2bf(v0.w * inv);
    o1.x = f2bf(v1.x * inv); o1.y = f2bf(v1.y * inv);
    o1.z = f2bf(v1.z * inv); o1.w = f2bf(v1.w * inv);
    ((ushort4*)xo)[t]       = o0;    // cached: GEMM's hot working set
    ((ushort4*)xo)[t + 256] = o1;
}

// ---- K2 mixed grid: [0,NPAIR) sym GEMM tiles | [NPAIR,+NRED) attn-mean reducers -----
__global__ __launch_bounds__(256) void k_mixed(const ushort* __restrict__ Xu,
                                               const float* __restrict__ attn,
                                               ushort* __restrict__ K16,
                                               double* __restrict__ sums,
                                               ushort* __restrict__ Amean) {
    __shared__ __align__(16) ushort lds_a[128 * 64];   // [row][64] bf16, swizzled chunks
    __shared__ __align__(16) ushort lds_b[128 * 64];
    const int t = threadIdx.x;
    const int batch = blockIdx.z;

    if (blockIdx.x >= NPAIR) {
        // ------- reducer: Amean[b,l,c] = mean_h attn[b,h,l,c] (bf16) -----------------
        const int rid = blockIdx.x - NPAIR;
        const float* ab = attn + (size_t)batch * H_DIM * L_DIM * L_DIM;
        ushort* am = Amean + (size_t)batch * L_DIM * L_DIM;
        int i = rid * 256 + t;
        #pragma unroll
        for (int j = 0; j < 8; ++j, i += NRED * 256) {   // 8 exact iters
            float4 s = {0.f, 0.f, 0.f, 0.f};
            #pragma unroll
            for (int h = 0; h < H_DIM; ++h) {
                // attn single-use streaming: bypass LLC so xu/K16/Amean stay resident
                const f4 v = __builtin_nontemporal_load(
                    ((const f4*)(ab + (size_t)h * L_DIM * L_DIM)) + i);
                s.x += v.x; s.y += v.y; s.z += v.z; s.w += v.w;
            }
            ushort4 o;
            o.x = f2bf(s.x * 0.125f); o.y = f2bf(s.y * 0.125f);
            o.z = f2bf(s.z * 0.125f); o.w = f2bf(s.w * 0.125f);
            ((ushort4*)am)[i] = o;               // cached: re-read by epilogue
        }
        return;
    }

    // ---------- GEMM tile (upper-triangular + mirror), BK=64 single-buffer -----------
    const int lane = t & 63;
    const int w    = t >> 6;
    const int wr   = w >> 1, wc = w & 1;       // 2x2 waves, 64x64 each
    int ti = 0, rem = blockIdx.x;
    while (rem >= NT - ti) { rem -= NT - ti; ++ti; }
    const int tj = ti + rem;
    const int bRow = ti * 128;
    const int bCol = tj * 128;
    const bool diag = (ti == tj);
    const ushort* Xb = Xu + (size_t)batch * L_DIM * D_DIM;

    // staging map: thread t covers row (t>>3) of each 32-row group, 16B chunk (t&7),
    // with store-side swizzle chunk^=(row&7) applied via pre-swizzled global source
    const int srow8  = t >> 3;                         // 0..31
    const int schunk = ((t & 7) ^ (srow8 & 7)) * 8;    // element col offset
    const ushort* gA = Xb + (size_t)(bRow + srow8) * D_DIM + schunk;
    const ushort* gB = Xb + (size_t)(bCol + srow8) * D_DIM + schunk;
    ushort* lA = lds_a + t * 8;
    ushort* lB = lds_b + t * 8;

    f32x4 acc[4][4] = {};
    const int frow = lane & 15;
    const int fk   = lane >> 4;

    for (int kt = 0; kt < NKT; ++kt) {
        __syncthreads();                       // prev compute done: LDS reusable
        const size_t ko = (size_t)kt * 64;
        #pragma unroll
        for (int i = 0; i < 4; ++i) {          // 4 call-sites x 32 rows each, A and B
            gload_lds16(gA + ko + (size_t)i * 32 * D_DIM, lA + i * 2048);
            gload_lds16(gB + ko + (size_t)i * 32 * D_DIM, lB + i * 2048);
        }
        __syncthreads();                       // vmcnt(0) drain: tile ready
        #pragma unroll
        for (int ks = 0; ks < 2; ++ks) {
            bf16x8 a[4], b[4];
            #pragma unroll
            for (int m = 0; m < 4; ++m) {
                const int R = wr * 64 + m * 16 + frow;
                a[m] = *(const bf16x8*)&lds_a[R * 64 + (((ks << 2) + fk) ^ (R & 7)) * 8];
            }
            #pragma unroll
            for (int n = 0; n < 4; ++n) {
                const int S = wc * 64 + n * 16 + frow;
                b[n] = *(const bf16x8*)&lds_b[S * 64 + (((ks << 2) + fk) ^ (S & 7)) * 8];
            }
            #pragma unroll
            for (int m = 0; m < 4; ++m)
                #pragma unroll
                for (int n = 0; n < 4; ++n)
                    acc[m][n] = __builtin_amdgcn_mfma_f32_16x16x32_bf16(a[m], b[n], acc[m][n], 0, 0, 0);
        }
    }

    ushort* Kb = K16 + (size_t)batch * L_DIM * L_DIM;
    float ps = 0.f, pss = 0.f;
    #pragma unroll
    for (int m = 0; m < 4; ++m) {
        #pragma unroll
        for (int n = 0; n < 4; ++n) {
            #pragma unroll
            for (int j = 0; j < 4; ++j) {
                const int r = bRow + wr * 64 + m * 16 + fk * 4 + j;
                const int c = bCol + wc * 64 + n * 16 + frow;
                const float v = acc[m][n][j];
                Kb[(size_t)r * L_DIM + c] = f2bf(v);   // bf16 intermediate (LLC-hot)
                ps += v; pss += v * v;
            }
            if (!diag) {
                // mirror: K[c][r..r+3] — contiguous ushort4 (8 B)
                const int rr  = bCol + wc * 64 + n * 16 + frow;
                const int cc0 = bRow + wr * 64 + m * 16 + fk * 4;
                ushort4 mq;
                mq.x = f2bf(acc[m][n][0]); mq.y = f2bf(acc[m][n][1]);
                mq.z = f2bf(acc[m][n][2]); mq.w = f2bf(acc[m][n][3]);
                *(ushort4*)&Kb[(size_t)rr * L_DIM + cc0] = mq;
            }
        }
    }
    if (!diag) { ps *= 2.f; pss *= 2.f; }      // off-diag values appear twice in K
    #pragma unroll
    for (int off = 32; off; off >>= 1) {
        ps  += __shfl_down(ps, off);
        pss += __shfl_down(pss, off);
    }
    __shared__ float redS[4], redSS[4];
    if (lane == 0) { redS[w] = ps; redSS[w] = pss; }
    __syncthreads();
    if (t == 0) {
        atomicAdd(&sums[batch * 2],     (double)(redS[0] + redS[1] + redS[2] + redS[3]));
        atomicAdd(&sums[batch * 2 + 1], (double)(redSS[0] + redSS[1] + redSS[2] + redSS[3]));
    }
}

// ------- K3: K_norm (f32, nt) from bf16 K; dot(Amean,K) -> cos_align, gate -----------
__global__ __launch_bounds__(256) void k_epilogue(float* __restrict__ out,
                                                  const ushort* __restrict__ K16,
                                                  const ushort* __restrict__ Amean,
                                                  const double* __restrict__ sums,
                                                  const float* __restrict__ Wp,
                                                  const float* __restrict__ bp) {
    const int row = blockIdx.x;              // b*L + l
    const int b = row >> 11;
    const int t = threadIdx.x;

    const double N = (double)L_DIM * (double)L_DIM;
    const double mean_d = sums[b * 2] / N;
    double var = (sums[b * 2 + 1] - N * mean_d * mean_d) / (N - 1.0);
    var = var > 0.0 ? var : 0.0;
    float sd = (float)sqrt(var);
    sd = fmaxf(sd, EPSV);
    const float inv_std = 1.0f / sd;
    const float mean = (float)mean_d;

    const ushort* krow = K16 + (size_t)row * L_DIM;
    const ushort* arow = Amean + (size_t)row * L_DIM;
    float* onrm = out + 2 * B_DIM * L_DIM + (size_t)row * L_DIM;

    // 8 elements per thread (both LLC-hot bf16 reads), f32 nt store
    const ushort4 k0 = ((const ushort4*)krow)[t * 2];
    const ushort4 k1 = ((const ushort4*)krow)[t * 2 + 1];
    const ushort4 a0 = ((const ushort4*)arow)[t * 2];
    const ushort4 a1 = ((const ushort4*)arow)[t * 2 + 1];
    float kf[8] = { bf2f(k0.x), bf2f(k0.y), bf2f(k0.z), bf2f(k0.w),
                    bf2f(k1.x), bf2f(k1.y), bf2f(k1.z), bf2f(k1.w) };
    float af[8] = { bf2f(a0.x), bf2f(a0.y), bf2f(a0.z), bf2f(a0.w),
                    bf2f(a1.x), bf2f(a1.y), bf2f(a1.z), bf2f(a1.w) };
    float dot = 0.f;
    #pragma unroll
    for (int j = 0; j < 8; ++j) dot += af[j] * kf[j];
    f4 n0, n1;
    n0.x = (kf[0] - mean) * inv_std; n0.y = (kf[1] - mean) * inv_std;
    n0.z = (kf[2] - mean) * inv_std; n0.w = (kf[3] - mean) * inv_std;
    n1.x = (kf[4] - mean) * inv_std; n1.y = (kf[5] - mean) * inv_std;
    n1.z = (kf[6] - mean) * inv_std; n1.w = (kf[7] - mean) * inv_std;
    __builtin_nontemporal_store(n0, ((f4*)onrm) + t * 2);   // written once, never read
    __builtin_nontemporal_store(n1, ((f4*)onrm) + t * 2 + 1);

    #pragma unroll
    for (int off = 32; off; off >>= 1) dot += __shfl_down(dot, off);
    __shared__ float red[4];
    if ((t & 63) == 0) red[t >> 6] = dot;
    __syncthreads();
    if (t == 0) {
        const float dotv = red[0] + red[1] + red[2] + red[3];
        const float ca = (dotv - mean) * inv_std;      // uses sum_c A == 1
        out[B_DIM * L_DIM + row] = ca;                 // cos_align
        const float z = Wp[0] * ca + bp[0];
        out[row] = 1.0f / (1.0f + expf(-z));           // gate
    }
}

extern "C" void kernel_launch(void* const* d_in, const int* in_sizes, int n_in,
                              void* d_out, int out_size, void* d_ws, size_t ws_size,
                              hipStream_t stream) {
    const float* x    = (const float*)d_in[0];
    const float* attn = (const float*)d_in[1];
    const float* W    = (const float*)d_in[2];
    const float* bb   = (const float*)d_in[3];
    float* out = (float*)d_out;

    const size_t MAT = (size_t)B_DIM * L_DIM * L_DIM;                 // 8.4M elems
    ushort* xu    = (ushort*)d_ws;                                    // 16.8 MB bf16
    double* sums  = (double*)((char*)d_ws + MAT * 2);
    ushort* Amean = (ushort*)((char*)d_ws + MAT * 2 + 256);           // 16.8 MB bf16
    ushort* K16   = (ushort*)((char*)d_ws + MAT * 4 + 256);           // 16.8 MB bf16

    hipLaunchKernelGGL(k_normalize, dim3(B_DIM * L_DIM), dim3(256), 0, stream,
                       x, xu, sums);
    hipLaunchKernelGGL(k_mixed, dim3(NPAIR + NRED, 1, B_DIM), dim3(256), 0, stream,
                       xu, attn, K16, sums, Amean);
    hipLaunchKernelGGL(k_epilogue, dim3(B_DIM * L_DIM), dim3(256), 0, stream,
                       out, K16, Amean, sums, W, bb);
}